// Round 5
// baseline (385.651 us; speedup 1.0000x reference)
//
#include <hip/hip_runtime.h>
#include <hip/hip_bf16.h>
#include <stdint.h>

#define NSK   1000
#define EMB   256
#define BB    32
#define SS    2048
#define TILE  128
#define NJT   (SS / TILE)             // 16
#define NUNIT (NJT * (NJT + 1) / 2)   // 136 tile-pairs per batch
#define BK    16                      // K-chunk = one MFMA k-step
#define NCHUNK (EMB / BK)             // 16

typedef __bf16 bf16x8 __attribute__((ext_vector_type(8)));
typedef float  f32x16 __attribute__((ext_vector_type(16)));
typedef float  f32x4  __attribute__((ext_vector_type(4)));

// bf16 table layout in workspace (element offsets)
#define OFF_AI 0                  // alpha_inter  [2000][256]
#define OFF_BI (2 * NSK * EMB)    // beta_inter   [2000][256]
#define OFF_AS (4 * NSK * EMB)    // alpha_skill  [1000][256]
#define OFF_BS (5 * NSK * EMB)    // beta_skill   [1000][256]
#define TOT_BF (6 * NSK * EMB)    // 1,536,000 elements = 3 MB

// also zeroes the output accumulator (d_out doubles as hsum; poisoned each launch)
__global__ void cvt_tables(const float* __restrict__ ai, const float* __restrict__ bi,
                           const float* __restrict__ as_, const float* __restrict__ bs,
                           __bf16* __restrict__ ws, float* __restrict__ acc) {
    int i = blockIdx.x * 256 + threadIdx.x;
    if (i < BB * SS) acc[i] = 0.0f;
    if (i >= TOT_BF) return;
    float v;
    if (i < OFF_AS) v = (i < OFF_BI) ? ai[i] : bi[i - OFF_BI];
    else            v = (i < OFF_BS) ? as_[i - OFF_AS] : bs[i - OFF_BS];
    ws[i] = (__bf16)v;
}

// rare duplicate-timestamp rescue: fp32 dot, single code copy (icache)
__device__ __attribute__((noinline)) float dot256(const float* __restrict__ a,
                                                  const float* __restrict__ b) {
    float s = 0.0f;
#pragma unroll 8
    for (int k = 0; k < EMB; ++k) s += a[k] * b[k];
    return s;
}

// one WG = one (b, jt, it) tile-pair; fragments gathered DIRECTLY from global
// (L2-resident 3MB table) in MFMA operand layout — no LDS staging, no K-loop
// barriers. Partial colsums atomically added into acc.
__global__ __launch_bounds__(256, 2) void hawkes_unit(
    const int* __restrict__ skills, const int* __restrict__ times,
    const int* __restrict__ labels, const __bf16* __restrict__ tab,
    const float* __restrict__ aiW_f, const float* __restrict__ asW_f,
    float* __restrict__ acc)
{
    __shared__ __align__(16) float  t_i[TILE];
    __shared__ __align__(16) float  t_j[TILE];
    __shared__ int   idx_i[TILE];
    __shared__ int   idx_j[TILE];
    __shared__ float colsum[TILE];

    const int u  = blockIdx.x;
    const int b  = u / NUNIT;
    const int p  = u - b * NUNIT;
    int jt = (int)((sqrtf(8.0f * (float)p + 1.0f) - 1.0f) * 0.5f);
    while ((jt + 1) * (jt + 2) / 2 <= p) ++jt;
    while (jt * (jt + 1) / 2 > p) --jt;
    const int it   = p - jt * (jt + 1) / 2;
    const bool diag = (it == jt);
    const int j0 = jt * TILE, i0 = it * TILE;

    const int tid = threadIdx.x;
    const int l   = tid & 63;
    const int w   = tid >> 6;
    const int wi  = w >> 1, wj = w & 1;       // 2x2 wave quadrants of 128x128
    const int lane31 = l & 31;
    const int khalf  = l >> 5;

    if (tid < TILE) {
        int j = j0 + tid;
        idx_j[tid] = skills[b * SS + j];
        t_j[tid]   = (float)times[b * SS + j] / 1000.0f;
        colsum[tid] = 0.0f;
    } else {
        int q = tid - TILE;
        int ii = i0 + q;
        idx_i[q] = skills[b * SS + ii] + labels[b * SS + ii] * NSK;
        t_i[q]   = (float)times[b * SS + ii] / 1000.0f;
    }
    __syncthreads();

    const float tj0 = t_j[wj * 64 + lane31];
    const float tj1 = t_j[wj * 64 + 32 + lane31];

    // per-lane fragment row pointers: A-operand layout = row (lane&31), k-half (lane>>5)
    const char* tb = (const char*)tab;
    const int rA0 = idx_i[(wi * 2 + 0) * 32 + lane31];
    const int rA1 = idx_i[(wi * 2 + 1) * 32 + lane31];
    const int rB0 = idx_j[(wj * 2 + 0) * 32 + lane31];
    const int rB1 = idx_j[(wj * 2 + 1) * 32 + lane31];
    const uint32_t kh = (uint32_t)khalf * 16;                 // byte offset of k-half
    const uint32_t oAI0 = (uint32_t)(OFF_AI * 2) + (uint32_t)rA0 * (EMB * 2) + kh;
    const uint32_t oAI1 = (uint32_t)(OFF_AI * 2) + (uint32_t)rA1 * (EMB * 2) + kh;
    const uint32_t oBI0 = (uint32_t)(OFF_BI * 2) + (uint32_t)rA0 * (EMB * 2) + kh;
    const uint32_t oBI1 = (uint32_t)(OFF_BI * 2) + (uint32_t)rA1 * (EMB * 2) + kh;
    const uint32_t oAS0 = (uint32_t)(OFF_AS * 2) + (uint32_t)rB0 * (EMB * 2) + kh;
    const uint32_t oAS1 = (uint32_t)(OFF_AS * 2) + (uint32_t)rB1 * (EMB * 2) + kh;
    const uint32_t oBS0 = (uint32_t)(OFF_BS * 2) + (uint32_t)rB0 * (EMB * 2) + kh;
    const uint32_t oBS1 = (uint32_t)(OFF_BS * 2) + (uint32_t)rB1 * (EMB * 2) + kh;

#define LOADF(dst, c)                                                          \
    do {                                                                       \
        uint32_t co = (uint32_t)(c) * (BK * 2);                                \
        dst[0] = *(const bf16x8*)(tb + oAI0 + co);                             \
        dst[1] = *(const bf16x8*)(tb + oAI1 + co);                             \
        dst[2] = *(const bf16x8*)(tb + oBI0 + co);                             \
        dst[3] = *(const bf16x8*)(tb + oBI1 + co);                             \
        dst[4] = *(const bf16x8*)(tb + oAS0 + co);                             \
        dst[5] = *(const bf16x8*)(tb + oAS1 + co);                             \
        dst[6] = *(const bf16x8*)(tb + oBS0 + co);                             \
        dst[7] = *(const bf16x8*)(tb + oBS1 + co);                             \
    } while (0)

    f32x16 accA[2][2], accB[2][2];
#pragma unroll
    for (int mi = 0; mi < 2; ++mi)
#pragma unroll
        for (int nj = 0; nj < 2; ++nj) { accA[mi][nj] = 0.0f; accB[mi][nj] = 0.0f; }

    bf16x8 frag[2][8];
    LOADF(frag[0], 0);

#pragma unroll
    for (int c = 0; c < NCHUNK; ++c) {
        const int cur = c & 1;
        if (c + 1 < NCHUNK) LOADF(frag[cur ^ 1], c + 1);   // in flight over MFMAs(c)
#pragma unroll
        for (int mi = 0; mi < 2; ++mi)
#pragma unroll
            for (int nj = 0; nj < 2; ++nj) {
                accA[mi][nj] = __builtin_amdgcn_mfma_f32_32x32x16_bf16(
                    frag[cur][0 + mi], frag[cur][4 + nj], accA[mi][nj], 0, 0, 0);
                accB[mi][nj] = __builtin_amdgcn_mfma_f32_32x32x16_bf16(
                    frag[cur][2 + mi], frag[cur][6 + nj], accB[mi][nj], 0, 0, 0);
            }
    }

    // ---- elementwise + column partial sums ----
    // C/D layout (32x32): col = lane&31, row = (reg&3) + 8*(reg>>2) + 4*(lane>>5)
    float csum0 = 0.0f, csum1 = 0.0f;
#pragma unroll
    for (int mi = 0; mi < 2; ++mi) {
        const int rbase = (wi * 2 + mi) * 32 + 4 * khalf;
        f32x4 tiv[4];
#pragma unroll
        for (int q = 0; q < 4; ++q) tiv[q] = *(const f32x4*)(t_i + rbase + 8 * q);
#pragma unroll
        for (int nj = 0; nj < 2; ++nj) {
            const float tjv = (nj == 0) ? tj0 : tj1;
            const int   jl  = wj * 64 + nj * 32 + lane31;
            float s = 0.0f;
#pragma unroll
            for (int r = 0; r < 16; ++r) {
                const int q = r >> 2, e = r & 3;
                const int il = rbase + 8 * q + e;
                if (diag && il >= jl) continue;   // strict upper triangle (i < j)
                float d = fabsf(tiv[q][e] - tjv);
                float alpha = accA[mi][nj][r];
                if (d == 0.0f)
                    alpha = dot256(aiW_f + (size_t)idx_i[il] * EMB,
                                   asW_f + (size_t)idx_j[jl] * EMB);
                // alpha * exp_nat(-beta*ln(d)/ln5) = alpha * exp2(-beta*log2(d)/ln5)
                float dl   = __builtin_amdgcn_logf(d + 1e-10f) * 0.6213349345596119f;
                float beta = accB[mi][nj][r] + 1.0f;
                beta = fminf(fmaxf(beta, 0.0f), 10.0f);
                s += alpha * __builtin_amdgcn_exp2f(-beta * dl);
            }
            if (nj == 0) csum0 += s; else csum1 += s;
        }
    }

    // ---- reduce to per-column sums, then one global atomic per column ----
    __syncthreads();
    csum0 += __shfl_xor(csum0, 32);
    csum1 += __shfl_xor(csum1, 32);
    if (l < 32) {
        atomicAdd(&colsum[wj * 64 + lane31], csum0);
        atomicAdd(&colsum[wj * 64 + 32 + lane31], csum1);
    }
    __syncthreads();
    if (tid < TILE)
        atomicAdd(&acc[b * SS + j0 + tid], colsum[tid]);
}

__global__ void hawkes_final(const int* __restrict__ skills, const int* __restrict__ problems,
                             const float* __restrict__ pbW, const float* __restrict__ sbW,
                             float* __restrict__ out) {
    int i = blockIdx.x * 256 + threadIdx.x;
    if (i >= BB * SS) return;
    float h = pbW[problems[i]] + sbW[skills[i]] + out[i];
    out[i] = 1.0f / (1.0f + __builtin_amdgcn_exp2f(-h * 1.4426950408889634f));
}

extern "C" void kernel_launch(void* const* d_in, const int* in_sizes, int n_in,
                              void* d_out, int out_size, void* d_ws, size_t ws_size,
                              hipStream_t stream) {
    const int*   skills   = (const int*)d_in[0];
    const int*   problems = (const int*)d_in[1];
    const int*   times    = (const int*)d_in[2];
    const int*   labels   = (const int*)d_in[3];
    const float* aiW      = (const float*)d_in[4];  // alpha_inter_W [2000,256]
    const float* asW      = (const float*)d_in[5];  // alpha_skill_W [1000,256]
    const float* biW      = (const float*)d_in[6];  // beta_inter_W  [2000,256]
    const float* bsW      = (const float*)d_in[7];  // beta_skill_W  [1000,256]
    const float* pbW      = (const float*)d_in[8];  // problem_base_W [20000,1]
    const float* sbW      = (const float*)d_in[9];  // skill_base_W   [1000,1]
    float* out = (float*)d_out;
    __bf16* tab = (__bf16*)d_ws;   // 3 MB

    cvt_tables<<<(TOT_BF + 255) / 256, 256, 0, stream>>>(aiW, biW, asW, bsW, tab, out);
    hawkes_unit<<<BB * NUNIT, 256, 0, stream>>>(skills, times, labels, tab, aiW, asW, out);
    hawkes_final<<<(BB * SS + 255) / 256, 256, 0, stream>>>(skills, problems, pbW, sbW, out);
}

// Round 6
// 331.496 us; speedup vs baseline: 1.1634x; 1.1634x over previous
//
#include <hip/hip_runtime.h>
#include <hip/hip_bf16.h>
#include <stdint.h>

#define NSK   1000
#define EMB   256
#define BB    32
#define SS    2048
#define TILE  128
#define NJT   (SS / TILE)             // 16
#define NUNIT (NJT * (NJT + 1) / 2)   // 136 tile-pairs per batch
#define BK    32                      // K-chunk (fp8 bytes per row per chunk = 32)
#define NCHUNK (EMB / BK)             // 8
#define SCALE_INV (1.0f / 4096.0f)    // undo (64x)^2 fp8 scaling

typedef float f32x16 __attribute__((ext_vector_type(16)));
typedef float f32x4  __attribute__((ext_vector_type(4)));
typedef long  longx2 __attribute__((ext_vector_type(2)));

// fp8 table layout in workspace (byte offsets; 1 B/elem)
#define OFF_AI8 0
#define OFF_BI8 (2 * NSK * EMB)   // 512000
#define OFF_AS8 (4 * NSK * EMB)   // 1024000
#define OFF_BS8 (5 * NSK * EMB)   // 1280000
#define TOT8    (6 * NSK * EMB)   // 1536000 bytes
#define DONE_OFF TOT8             // 512 ints after the table

// XOR swizzle: flip bit5 (32B) based on bit9 (512B) — breaks the 512B-stride
// write conflict while keeping reads lane-linear (bit9 is wave-uniform there).
#define SWZ(a) ((a) ^ ((((a) >> 9) & 1) << 5))

// convert 4 tables fp32 -> fp8 e4m3 (x64), zero acc + done counters
__global__ void cvt_tables(const float* __restrict__ ai, const float* __restrict__ bi,
                           const float* __restrict__ as_, const float* __restrict__ bs,
                           int* __restrict__ ws8, float* __restrict__ acc,
                           int* __restrict__ done) {
    int g = blockIdx.x * 256 + threadIdx.x;   // one 4-elem group per thread
    if (g < BB * SS) acc[g] = 0.0f;
    if (g < BB * NJT) done[g] = 0;
    if (g * 4 >= TOT8) return;
    int e = g * 4;
    const float* src; int off;
    if (e < OFF_AS8) { if (e < OFF_BI8) { src = ai;  off = e; }
                       else             { src = bi;  off = e - OFF_BI8; } }
    else             { if (e < OFF_BS8) { src = as_; off = e - OFF_AS8; }
                       else             { src = bs;  off = e - OFF_BS8; } }
    const float4 v = *(const float4*)(src + off);
    int lo = __builtin_amdgcn_cvt_pk_fp8_f32(v.x * 64.0f, v.y * 64.0f, 0, false);
    int wd = __builtin_amdgcn_cvt_pk_fp8_f32(v.z * 64.0f, v.w * 64.0f, lo, true);
    ws8[g] = wd;
}

// rare duplicate-timestamp rescue: fp32 dot, single code copy
__device__ __attribute__((noinline)) float dot256(const float* __restrict__ a,
                                                  const float* __restrict__ b) {
    float s = 0.0f;
#pragma unroll 8
    for (int k = 0; k < EMB; ++k) s += a[k] * b[k];
    return s;
}

// one WG = one (b, jt, it) tile-pair. fp8 LDS staging (XOR-swizzled,
// double-buffered), fp8 MFMA, fused epilogue via per-(b,jt) done counter.
__global__ __launch_bounds__(256, 2) void hawkes_unit(
    const int* __restrict__ skills, const int* __restrict__ problems,
    const int* __restrict__ times,  const int* __restrict__ labels,
    const unsigned char* __restrict__ tab,
    const float* __restrict__ aiW_f, const float* __restrict__ asW_f,
    const float* __restrict__ biW_f, const float* __restrict__ bsW_f,
    const float* __restrict__ pbW,   const float* __restrict__ sbW,
    int* __restrict__ done, float* __restrict__ acc)
{
    // per buffer: 4 mats x 4 mblks x 2 ksteps x 64 lanes x 8B = 16 KB
    __shared__ __align__(16) char  sbuf[2 * 16384];   // 32 KB
    __shared__ __align__(16) float t_i[TILE];
    __shared__ __align__(16) float t_j[TILE];
    __shared__ int   idx_i[TILE];
    __shared__ int   idx_j[TILE];
    __shared__ float colsum[TILE];
    __shared__ int   lastflag;

    const int u  = blockIdx.x;
    const int b  = u / NUNIT;
    const int p  = u - b * NUNIT;
    int jt = (int)((sqrtf(8.0f * (float)p + 1.0f) - 1.0f) * 0.5f);
    while ((jt + 1) * (jt + 2) / 2 <= p) ++jt;
    while (jt * (jt + 1) / 2 > p) --jt;
    const int it   = p - jt * (jt + 1) / 2;
    const bool diag = (it == jt);
    const int j0 = jt * TILE, i0 = it * TILE;

    const int tid = threadIdx.x;
    const int l   = tid & 63;
    const int w   = tid >> 6;
    const int wi  = w >> 1, wj = w & 1;       // 2x2 wave quadrants of 128x128
    const int lane31 = l & 31;
    const int khalf  = l >> 5;

    if (tid < TILE) {
        int j = j0 + tid;
        idx_j[tid] = skills[b * SS + j];
        t_j[tid]   = (float)times[b * SS + j] / 1000.0f;
        colsum[tid] = 0.0f;
    } else {
        int q = tid - TILE;
        int ii = i0 + q;
        idx_i[q] = skills[b * SS + ii] + labels[b * SS + ii] * NSK;
        t_i[q]   = (float)times[b * SS + ii] / 1000.0f;
    }
    __syncthreads();

    const float tj0 = t_j[wj * 64 + lane31];
    const float tj1 = t_j[wj * 64 + 32 + lane31];

    // staging: wave w stages matrix w. lane l: row m*32+(l>>1), bytes (l&1)*16..+15
    // of each 32B row-chunk (pair-coalesced 32B global segments).
    const unsigned char* my_tab = tab + ((w == 0) ? OFF_AI8 : (w == 1) ? OFF_BI8
                                       : (w == 2) ? OFF_AS8 : OFF_BS8);
    const int* my_idx = (w < 2) ? idx_i : idx_j;
    const unsigned char* rowptr[4];
#pragma unroll
    for (int m = 0; m < 4; ++m)
        rowptr[m] = my_tab + (size_t)my_idx[m * 32 + (l >> 1)] * EMB + (l & 1) * 16;

    // write dests: 16B = k-step (l&1); low 8B -> frag lane (l>>1), high 8B -> 32+(l>>1)
    int wo1[4];
#pragma unroll
    for (int m = 0; m < 4; ++m)
        wo1[m] = w * 4096 + m * 1024 + (l & 1) * 512 + (l >> 1) * 8;

    longx2 sreg[4];
#define LOADC(c)                                                       \
    do { _Pragma("unroll")                                             \
        for (int m = 0; m < 4; ++m)                                    \
            sreg[m] = *(const longx2*)(rowptr[m] + (c) * BK);          \
    } while (0)
#define WRITEC(buf)                                                    \
    do { char* db = sbuf + (buf) * 16384;                              \
        _Pragma("unroll")                                              \
        for (int m = 0; m < 4; ++m) {                                  \
            *(long*)(db + SWZ(wo1[m]))       = sreg[m].x;              \
            *(long*)(db + SWZ(wo1[m] + 256)) = sreg[m].y;              \
        }                                                              \
    } while (0)

    f32x16 accA[2][2], accB[2][2];
#pragma unroll
    for (int mi = 0; mi < 2; ++mi)
#pragma unroll
        for (int nj = 0; nj < 2; ++nj) { accA[mi][nj] = 0.0f; accB[mi][nj] = 0.0f; }

    LOADC(0);
    WRITEC(0);

    for (int c = 0; c < NCHUNK; ++c) {
        const int cur = c & 1;
        if (c + 1 < NCHUNK) LOADC(c + 1);   // global->reg, in flight over compute(c)
        __syncthreads();                     // publishes chunk c's ds_writes

        const char* sb = sbuf + cur * 16384;
#pragma unroll
        for (int ks = 0; ks < 2; ++ks) {
            const int lsw = (l * 8) ^ (ks * 32);   // SWZ with wave-uniform bit9=ks
            long fa[2], fb[2], ga[2], gb[2];
#pragma unroll
            for (int mi = 0; mi < 2; ++mi) {
                int mb = (wi * 2 + mi) * 1024 + ks * 512;
                fa[mi] = *(const long*)(sb + 0    + mb + lsw);
                fb[mi] = *(const long*)(sb + 4096 + mb + lsw);
            }
#pragma unroll
            for (int nj = 0; nj < 2; ++nj) {
                int nb = (wj * 2 + nj) * 1024 + ks * 512;
                ga[nj] = *(const long*)(sb + 8192  + nb + lsw);
                gb[nj] = *(const long*)(sb + 12288 + nb + lsw);
            }
#pragma unroll
            for (int mi = 0; mi < 2; ++mi)
#pragma unroll
                for (int nj = 0; nj < 2; ++nj) {
                    accA[mi][nj] = __builtin_amdgcn_mfma_f32_32x32x16_fp8_fp8(
                        fa[mi], ga[nj], accA[mi][nj], 0, 0, 0);
                    accB[mi][nj] = __builtin_amdgcn_mfma_f32_32x32x16_fp8_fp8(
                        fb[mi], gb[nj], accB[mi][nj], 0, 0, 0);
                }
        }
        if (c + 1 < NCHUNK) WRITEC(cur ^ 1);
    }

    // ---- elementwise + column partial sums ----
    // C/D layout (32x32): col = lane&31, row = (reg&3) + 8*(reg>>2) + 4*(lane>>5)
    float csum0 = 0.0f, csum1 = 0.0f;
#pragma unroll
    for (int mi = 0; mi < 2; ++mi) {
        const int rbase = (wi * 2 + mi) * 32 + 4 * khalf;
        f32x4 tiv[4];
#pragma unroll
        for (int q = 0; q < 4; ++q) tiv[q] = *(const f32x4*)(t_i + rbase + 8 * q);
#pragma unroll
        for (int nj = 0; nj < 2; ++nj) {
            const float tjv = (nj == 0) ? tj0 : tj1;
            const int   jl  = wj * 64 + nj * 32 + lane31;
            float s = 0.0f;
#pragma unroll
            for (int r = 0; r < 16; ++r) {
                const int q = r >> 2, e = r & 3;
                const int il = rbase + 8 * q + e;
                if (diag && il >= jl) continue;   // strict upper triangle (i < j)
                float d = fabsf(tiv[q][e] - tjv);
                float alpha, braw;
                if (d == 0.0f) {   // huge exp amplification: fp32 both dots
                    alpha = dot256(aiW_f + (size_t)idx_i[il] * EMB,
                                   asW_f + (size_t)idx_j[jl] * EMB);
                    braw  = dot256(biW_f + (size_t)idx_i[il] * EMB,
                                   bsW_f + (size_t)idx_j[jl] * EMB);
                } else {
                    alpha = accA[mi][nj][r] * SCALE_INV;
                    braw  = accB[mi][nj][r] * SCALE_INV;
                }
                // alpha * exp_nat(-beta*ln(d)/ln5) = alpha * exp2(-beta*log2(d)/ln5)
                float dl   = __builtin_amdgcn_logf(d + 1e-10f) * 0.6213349345596119f;
                float beta = fminf(fmaxf(braw + 1.0f, 0.0f), 10.0f);
                s += alpha * __builtin_amdgcn_exp2f(-beta * dl);
            }
            if (nj == 0) csum0 += s; else csum1 += s;
        }
    }

    // ---- reduce, add to global acc, last unit of (b,jt) applies epilogue ----
    __syncthreads();
    csum0 += __shfl_xor(csum0, 32);
    csum1 += __shfl_xor(csum1, 32);
    if (l < 32) {
        atomicAdd(&colsum[wj * 64 + lane31], csum0);
        atomicAdd(&colsum[wj * 64 + 32 + lane31], csum1);
    }
    __syncthreads();
    if (tid < TILE)
        atomicAdd(&acc[b * SS + j0 + tid], colsum[tid]);

    __syncthreads();
    if (tid == 0) {
        __threadfence();                          // release our acc atomics
        int old = atomicAdd(&done[b * NJT + jt], 1);
        lastflag = (old == jt);                   // all jt+1 units done?
    }
    __syncthreads();
    if (lastflag && tid < TILE) {
        __threadfence();                          // acquire
        int j = b * SS + j0 + tid;
        float v = __hip_atomic_load(&acc[j], __ATOMIC_RELAXED, __HIP_MEMORY_SCOPE_AGENT);
        float h = pbW[problems[j]] + sbW[skills[j]] + v;
        acc[j] = 1.0f / (1.0f + __builtin_amdgcn_exp2f(-h * 1.4426950408889634f));
    }
}

extern "C" void kernel_launch(void* const* d_in, const int* in_sizes, int n_in,
                              void* d_out, int out_size, void* d_ws, size_t ws_size,
                              hipStream_t stream) {
    const int*   skills   = (const int*)d_in[0];
    const int*   problems = (const int*)d_in[1];
    const int*   times    = (const int*)d_in[2];
    const int*   labels   = (const int*)d_in[3];
    const float* aiW      = (const float*)d_in[4];  // alpha_inter_W [2000,256]
    const float* asW      = (const float*)d_in[5];  // alpha_skill_W [1000,256]
    const float* biW      = (const float*)d_in[6];  // beta_inter_W  [2000,256]
    const float* bsW      = (const float*)d_in[7];  // beta_skill_W  [1000,256]
    const float* pbW      = (const float*)d_in[8];  // problem_base_W [20000,1]
    const float* sbW      = (const float*)d_in[9];  // skill_base_W   [1000,1]
    float* out = (float*)d_out;                     // doubles as accumulator
    unsigned char* tab = (unsigned char*)d_ws;      // 1.5 MB fp8 tables
    int* done = (int*)(tab + DONE_OFF);             // 512 counters

    cvt_tables<<<(TOT8 / 4 + 255) / 256, 256, 0, stream>>>(
        aiW, biW, asW, bsW, (int*)tab, out, done);
    hawkes_unit<<<BB * NUNIT, 256, 0, stream>>>(
        skills, problems, times, labels, tab, aiW, asW, biW, bsW, pbW, sbW, done, out);
}